// Round 2
// baseline (18302.350 us; speedup 1.0000x reference)
//
#include <hip/hip_runtime.h>
#include <hip/hip_bf16.h>
#include <stdint.h>

typedef float f32x4 __attribute__((ext_vector_type(4)));
typedef short bf16x8 __attribute__((ext_vector_type(8)));

#define DEVINL static __device__ __forceinline__

// ---------------- problem dims ----------------
constexpr int BATCH = 256, SEQ = 512, IDIM = 512, HDIM = 512;
constexpr int NG  = 8;    // row groups, CONTIGUOUS bids: gi = bid>>5
constexpr int WC  = 32;   // wgs per group (column split)
constexpr int RPG = 32;   // batch rows per group
constexpr int CPW = 16;   // h-columns per wg

// ---------------- LDS map (bytes), all XOR-swizzled ----------------
constexpr int HP_OFF  = 0;        // h / rh tile [32 rows][512 k] bf16   (32KB)
constexpr int WGS_OFF = 32768;    // Wg stripe [32 cols][1024 k] bf16    (64KB)
constexpr int WHS_OFF = 98304;    // Wh stripe [16 cols][1024 k] bf16    (32KB)
constexpr int WO1_OFF = 131072;   // Wo1 stripe [16 cols][512 k] bf16    (16KB, cols 8..15 zero)
constexpr int SMEM_BYTES = 147456;

// ---------------- ws map (bytes) ----------------
constexpr size_t WS_H32 = 1024;                    // fp32 h master [256][512]  (512KB)
constexpr size_t WS_HBF = WS_H32 + 524288;         // bf16 h        [256][512]  (256KB)
constexpr size_t WS_RH  = WS_HBF + 262144;         // bf16 reset*h  [256][512]  (256KB)
constexpr size_t WS_NEEDED = WS_RH + 262144;       // ~1.05 MB, all zeroed per call

DEVINL short f2bf(float f) {
  uint32_t u = __float_as_uint(f);
  u += 0x7FFFu + ((u >> 16) & 1u);           // RNE
  return (short)(u >> 16);
}
DEVINL int hp_off (int row, int k) { return HP_OFF  + row * 1024 + ((k * 2) ^ ((row & 7) << 4)); }
DEVINL int wgs_off(int c,   int k) { return WGS_OFF + c   * 2048 + ((k * 2) ^ ((c   & 7) << 4)); }
DEVINL int whs_off(int c,   int k) { return WHS_OFF + c   * 2048 + ((k * 2) ^ ((c   & 7) << 4)); }
DEVINL int wo1_off(int c,   int k) { return WO1_OFF + c   * 1024 + ((k * 2) ^ ((c   & 7) << 4)); }
DEVINL float sigm(float v) { return 1.f / (1.f + __expf(-v)); }

__global__ void __launch_bounds__(256, 1) init_ys_kernel(float* out, const float* bo2) {
  int i = blockIdx.x * 256 + threadIdx.x;
  if (i < BATCH * SEQ) out[i] = bo2[0];
}

__global__ void __launch_bounds__(256, 1) gru_persist(
    const float* __restrict__ x,  const float* __restrict__ Wg, const float* __restrict__ bg,
    const float* __restrict__ Wh, const float* __restrict__ bh,
    const float* __restrict__ Wo1,const float* __restrict__ bo1,
    const float* __restrict__ Wo2,const float* __restrict__ bo2,
    float* __restrict__ out, char* __restrict__ ws)
{
  extern __shared__ char smem[];
  const int bid  = blockIdx.x;
  const int gi   = bid >> 5;       // contiguous row group (graceful if <256 CUs)
  const int j    = bid & 31;       // 0..31 within group
  const int tid  = threadIdx.x;
  const int lane = tid & 63;
  const int wave = tid >> 6;       // 0..3
  const int rowbase = gi * RPG;    // batch row base
  const int colbase = j * CPW;     // h-col base

  uint32_t* cntA = (uint32_t*)ws;         // [8]
  uint32_t* cntB = (uint32_t*)(ws + 64);  // [8]
  float* h32 = (float*)(ws + WS_H32);
  short* hbf = (short*)(ws + WS_HBF);
  short* rhbf= (short*)(ws + WS_RH);

  // ---------------- init: weights -> LDS ----------------
  // Wg stripe: local col c<16 => update col (colbase+c); else reset col (512+colbase+c-16)
  for (int it = 0; it < 128; ++it) {
    int c = tid & 31;
    int k = (tid >> 5) + it * 8;
    int cg = (c < 16) ? (colbase + c) : (512 + colbase + (c - 16));
    *(short*)(smem + wgs_off(c, k)) = f2bf(Wg[(size_t)k * 1024 + cg]);
  }
  // Wh stripe (full K: x-part k<512, h-part k>=512)
  for (int it = 0; it < 64; ++it) {
    int c = tid & 15;
    int k = (tid >> 4) + it * 16;
    *(short*)(smem + whs_off(c, k)) = f2bf(Wh[(size_t)k * 512 + colbase + c]);
  }
  // Wo1 stripe: cols 0..7 = midcols j*8..j*8+8, cols 8..15 zero
  for (int it = 0; it < 32; ++it) {
    int c = tid & 15;
    int k = (tid >> 4) + it * 16;
    *(short*)(smem + wo1_off(c, k)) = (c < 8) ? f2bf(Wo1[(size_t)k * 256 + j * 8 + c]) : (short)0;
  }
  // per-lane constants
  const int lc = lane & 15;
  const float bgu  = bg[colbase + lc];
  const float bgr  = bg[512 + colbase + lc];
  const float bhc  = bh[colbase + lc];
  const float bo1c = (lc < 8) ? bo1[j * 8 + lc] : 0.f;
  const float wo2c = (lc < 8) ? Wo2[j * 8 + lc] : 0.f;
  __syncthreads();

  const int mt    = wave & 1;            // M-tile (rows 16*mt..)
  const int ctile = wave >> 1;           // 0 = update cols, 1 = reset cols
  const int arow  = mt * 16 + (lane & 15);   // A-frag row within group tile
  const int kl    = (lane >> 4) * 8;         // A/B-frag k sub-offset
  const int bcol  = ctile * 16 + (lane & 15);// B col within Wg stripe

  float uvals[4] = {0.f, 0.f, 0.f, 0.f};

  for (int t = 0; t < SEQ; ++t) {
    // ---- A: load x_t A-frags into registers (no h dependence) ----
    bf16x8 xa[16];
    {
      const float* xrow = x + ((size_t)(rowbase + arow) * SEQ + t) * IDIM + kl;
#pragma unroll
      for (int ks = 0; ks < 16; ++ks) {
        float4 a = *(const float4*)(xrow + ks * 32);
        float4 b = *(const float4*)(xrow + ks * 32 + 4);
        bf16x8 v;
        v[0] = f2bf(a.x); v[1] = f2bf(a.y); v[2] = f2bf(a.z); v[3] = f2bf(a.w);
        v[4] = f2bf(b.x); v[5] = f2bf(b.y); v[6] = f2bf(b.z); v[7] = f2bf(b.w);
        xa[ks] = v;
      }
    }

    // ---- B: gates x-part MFMA (overlaps the inter-block wait below) ----
    f32x4 acc0 = {0.f, 0.f, 0.f, 0.f}, acc1 = {0.f, 0.f, 0.f, 0.f};
#pragma unroll
    for (int ks = 0; ks < 16; ks += 2) {
      bf16x8 b0 = *(const bf16x8*)(smem + wgs_off(bcol, ks * 32 + kl));
      acc0 = __builtin_amdgcn_mfma_f32_16x16x32_bf16(xa[ks], b0, acc0, 0, 0, 0);
      bf16x8 b1 = *(const bf16x8*)(smem + wgs_off(bcol, (ks + 1) * 32 + kl));
      acc1 = __builtin_amdgcn_mfma_f32_16x16x32_bf16(xa[ks + 1], b1, acc1, 0, 0, 0);
    }

    // ---- C: wait h_{t-1} complete for this group ----
    if (t > 0) {
      if (tid == 0)
        while (__hip_atomic_load(&cntB[gi], __ATOMIC_ACQUIRE, __HIP_MEMORY_SCOPE_AGENT) < (uint32_t)(WC * t))
          __builtin_amdgcn_s_sleep(1);
    }
    __syncthreads();

    // ---- D: stage h_{t-1} (bf16) into hpart ----
    for (int c = tid; c < RPG * 64; c += 256) {
      int row = c >> 6, kc = c & 63;
      bf16x8 v = *(const bf16x8*)(hbf + (size_t)(rowbase + row) * HDIM + kc * 8);
      *(bf16x8*)(smem + hp_off(row, kc * 8)) = v;
    }
    __syncthreads();

    // ---- E: gates h-part MFMA ----
#pragma unroll
    for (int ks = 0; ks < 16; ks += 2) {
      bf16x8 a0 = *(const bf16x8*)(smem + hp_off(arow, ks * 32 + kl));
      bf16x8 b0 = *(const bf16x8*)(smem + wgs_off(bcol, 512 + ks * 32 + kl));
      acc0 = __builtin_amdgcn_mfma_f32_16x16x32_bf16(a0, b0, acc0, 0, 0, 0);
      bf16x8 a1 = *(const bf16x8*)(smem + hp_off(arow, (ks + 1) * 32 + kl));
      bf16x8 b1 = *(const bf16x8*)(smem + wgs_off(bcol, 512 + (ks + 1) * 32 + kl));
      acc1 = __builtin_amdgcn_mfma_f32_16x16x32_bf16(a1, b1, acc1, 0, 0, 0);
    }
    f32x4 g = acc0 + acc1;

    // ---- F: gate nonlinearity ----
    if (ctile == 0) {           // update gate, kept in regs
#pragma unroll
      for (int ri = 0; ri < 4; ++ri) uvals[ri] = sigm(g[ri] + bgu);
    } else {                    // reset gate -> rh = r * h (fp32 master), store bf16
#pragma unroll
      for (int ri = 0; ri < 4; ++ri) {
        float r = sigm(g[ri] + bgr);
        int row = mt * 16 + (lane >> 4) * 4 + ri;
        int b = rowbase + row, c = colbase + lc;
        float hv = h32[(size_t)b * HDIM + c];
        rhbf[(size_t)b * HDIM + c] = f2bf(r * hv);
      }
    }

    // ---- G: head for y_{t-1} (h_{t-1} still staged in hpart) ----
    if (t > 0 && ctile == 1) {
      f32x4 ha = {0.f, 0.f, 0.f, 0.f};
#pragma unroll
      for (int ks = 0; ks < 16; ++ks) {
        bf16x8 a = *(const bf16x8*)(smem + hp_off(arow, ks * 32 + kl));
        bf16x8 b = *(const bf16x8*)(smem + wo1_off(lane & 15, ks * 32 + kl));
        ha = __builtin_amdgcn_mfma_f32_16x16x32_bf16(a, b, ha, 0, 0, 0);
      }
#pragma unroll
      for (int ri = 0; ri < 4; ++ri) {
        float z = fmaxf(ha[ri] + bo1c, 0.f) * wo2c;
        z += __shfl_xor(z, 1); z += __shfl_xor(z, 2);
        z += __shfl_xor(z, 4); z += __shfl_xor(z, 8);
        if (lc == 0) {
          int row = rowbase + mt * 16 + (lane >> 4) * 4 + ri;
          unsafeAtomicAdd(&out[(size_t)row * SEQ + (t - 1)], z);
        }
      }
    }

    // ---- H: publish rh ----
    __syncthreads();
    if (tid == 0)
      __hip_atomic_fetch_add(&cntA[gi], 1u, __ATOMIC_RELEASE, __HIP_MEMORY_SCOPE_AGENT);

    // ---- I: wait all rh stripes of this group ----
    if (tid == 0)
      while (__hip_atomic_load(&cntA[gi], __ATOMIC_ACQUIRE, __HIP_MEMORY_SCOPE_AGENT) < (uint32_t)(WC * (t + 1)))
        __builtin_amdgcn_s_sleep(1);
    __syncthreads();

    // ---- J: stage rh into hpart ----
    for (int c = tid; c < RPG * 64; c += 256) {
      int row = c >> 6, kc = c & 63;
      bf16x8 v = *(const bf16x8*)(rhbf + (size_t)(rowbase + row) * HDIM + kc * 8);
      *(bf16x8*)(smem + hp_off(row, kc * 8)) = v;
    }
    __syncthreads();

    // ---- K: cand MFMA + h update (ctile 0 waves) ----
    if (ctile == 0) {
      f32x4 ca = {0.f, 0.f, 0.f, 0.f}, cb = {0.f, 0.f, 0.f, 0.f};
#pragma unroll
      for (int ks = 0; ks < 16; ++ks) {
        bf16x8 bx = *(const bf16x8*)(smem + whs_off(lane & 15, ks * 32 + kl));
        ca = __builtin_amdgcn_mfma_f32_16x16x32_bf16(xa[ks], bx, ca, 0, 0, 0);
        bf16x8 a2 = *(const bf16x8*)(smem + hp_off(arow, ks * 32 + kl));
        bf16x8 bh2= *(const bf16x8*)(smem + whs_off(lane & 15, 512 + ks * 32 + kl));
        cb = __builtin_amdgcn_mfma_f32_16x16x32_bf16(a2, bh2, cb, 0, 0, 0);
      }
      f32x4 cc = ca + cb;
#pragma unroll
      for (int ri = 0; ri < 4; ++ri) {
        int row = mt * 16 + (lane >> 4) * 4 + ri;
        int b = rowbase + row, c = colbase + lc;
        float cand = tanhf(cc[ri] + bhc);
        float hold = h32[(size_t)b * HDIM + c];
        float u = uvals[ri];
        float hnew = (1.f - u) * hold + u * cand;
        h32[(size_t)b * HDIM + c] = hnew;
        hbf[(size_t)b * HDIM + c] = f2bf(hnew);
        if (t == SEQ - 1) out[(size_t)(BATCH * SEQ) + (size_t)b * HDIM + c] = hnew;
      }
    }

    // ---- L: publish h_t ----
    __syncthreads();
    if (tid == 0)
      __hip_atomic_fetch_add(&cntB[gi], 1u, __ATOMIC_RELEASE, __HIP_MEMORY_SCOPE_AGENT);
  }

  // ---------------- epilogue: y_{T-1} ----------------
  if (tid == 0)
    while (__hip_atomic_load(&cntB[gi], __ATOMIC_ACQUIRE, __HIP_MEMORY_SCOPE_AGENT) < (uint32_t)(WC * SEQ))
      __builtin_amdgcn_s_sleep(1);
  __syncthreads();
  for (int c = tid; c < RPG * 64; c += 256) {
    int row = c >> 6, kc = c & 63;
    bf16x8 v = *(const bf16x8*)(hbf + (size_t)(rowbase + row) * HDIM + kc * 8);
    *(bf16x8*)(smem + hp_off(row, kc * 8)) = v;
  }
  __syncthreads();
  if (ctile == 1) {
    f32x4 ha = {0.f, 0.f, 0.f, 0.f};
#pragma unroll
    for (int ks = 0; ks < 16; ++ks) {
      bf16x8 a = *(const bf16x8*)(smem + hp_off(arow, ks * 32 + kl));
      bf16x8 b = *(const bf16x8*)(smem + wo1_off(lane & 15, ks * 32 + kl));
      ha = __builtin_amdgcn_mfma_f32_16x16x32_bf16(a, b, ha, 0, 0, 0);
    }
#pragma unroll
    for (int ri = 0; ri < 4; ++ri) {
      float z = fmaxf(ha[ri] + bo1c, 0.f) * wo2c;
      z += __shfl_xor(z, 1); z += __shfl_xor(z, 2);
      z += __shfl_xor(z, 4); z += __shfl_xor(z, 8);
      if (lc == 0) {
        int row = rowbase + mt * 16 + (lane >> 4) * 4 + ri;
        unsafeAtomicAdd(&out[(size_t)row * SEQ + (SEQ - 1)], z);
      }
    }
  }
}

extern "C" void kernel_launch(void* const* d_in, const int* in_sizes, int n_in,
                              void* d_out, int out_size, void* d_ws, size_t ws_size,
                              hipStream_t stream) {
  const float* x   = (const float*)d_in[0];
  const float* Wg  = (const float*)d_in[1];
  const float* bg  = (const float*)d_in[2];
  const float* Wh  = (const float*)d_in[3];
  const float* bh  = (const float*)d_in[4];
  const float* Wo1 = (const float*)d_in[5];
  const float* bo1 = (const float*)d_in[6];
  const float* Wo2 = (const float*)d_in[7];
  const float* bo2 = (const float*)d_in[8];
  float* out = (float*)d_out;
  char*  ws  = (char*)d_ws;
  if (ws_size < WS_NEEDED) return;   // ~1.05 MB — well under any sane scratch

  // zero counters + h buffers (deterministic per call / per replay)
  hipMemsetAsync(ws, 0, WS_NEEDED, stream);
  // ys := bo2 (head partials are atomically accumulated on top)
  init_ys_kernel<<<dim3(512), dim3(256), 0, stream>>>(out, bo2);

  (void)hipFuncSetAttribute((const void*)gru_persist,
                            hipFuncAttributeMaxDynamicSharedMemorySize, SMEM_BYTES);

  // Regular launch: 256 blocks × 144KB LDS → exactly 1 block/CU, grid == CU
  // count → all blocks co-resident (persistent-kernel pattern, no coop API).
  gru_persist<<<dim3(NG * WC), dim3(256), SMEM_BYTES, stream>>>(
      x, Wg, bg, Wh, bh, Wo1, bo1, Wo2, bo2, out, ws);
}

// Round 3
// 9107.710 us; speedup vs baseline: 2.0095x; 2.0095x over previous
//
#include <hip/hip_runtime.h>
#include <hip/hip_bf16.h>
#include <stdint.h>

typedef float f32x4 __attribute__((ext_vector_type(4)));
typedef short bf16x8 __attribute__((ext_vector_type(8)));
typedef int   i32x4  __attribute__((ext_vector_type(4)));

#define DEVINL static __device__ __forceinline__

// ---------------- problem dims ----------------
constexpr int BATCH = 256, SEQ = 512, IDIM = 512, HDIM = 512;
constexpr int NG  = 8;    // row groups; gi = bid & 7 (XCD round-robin assumption, perf-only)
constexpr int WC  = 32;   // wgs per group (column split)
constexpr int RPG = 32;   // batch rows per group
constexpr int CPW = 16;   // h-columns per wg

// ---------------- LDS map (bytes) ----------------
constexpr int WGS_OFF = 0;        // Wg stripe [32 cols][1024 k] bf16 (64KB), XOR-swizzled
constexpr int WHS_OFF = 65536;    // Wh stripe [16 cols][1024 k] bf16 (32KB)
constexpr int WO1_OFF = 98304;    // Wo1 stripe [16 cols][512 k] bf16 (16KB, cols 8..15 zero)
constexpr int H32_OFF = 114688;   // fp32 h master [32 rows][17 pad] (2176B, block-private)
constexpr int SMEM_BYTES = H32_OFF + 32 * 17 * 4;   // 116864

// ---------------- ws map (bytes) ----------------
constexpr size_t FLAGA_OFF = 0;      // [8 groups][64 slots] u32  (rh published)
constexpr size_t FLAGB_OFF = 2048;   // [8 groups][64 slots] u32  (h published)
constexpr size_t HBF_OFF   = 4096;            // bf16 h  [256][512] (256KB) - no init needed
constexpr size_t RHBF_OFF  = 4096 + 262144;   // bf16 r*h[256][512] (256KB) - no init needed
constexpr size_t WS_NEEDED = RHBF_OFF + 262144;
constexpr size_t WS_ZERO   = 4096;   // only the flag arrays get memset

DEVINL short f2bf(float f) {
  uint32_t u = __float_as_uint(f);
  u += 0x7FFFu + ((u >> 16) & 1u);   // RNE
  return (short)(u >> 16);
}
DEVINL int wgs_off(int c, int k) { return WGS_OFF + c * 2048 + ((k * 2) ^ ((c & 7) << 4)); }
DEVINL int whs_off(int c, int k) { return WHS_OFF + c * 2048 + ((k * 2) ^ ((c & 7) << 4)); }
DEVINL int wo1_off(int c, int k) { return WO1_OFF + c * 1024 + ((k * 2) ^ ((c & 7) << 4)); }
DEVINL int h32_off(int row, int c) { return H32_OFF + (row * 17 + c) * 4; }
DEVINL float sigm(float v) { return 1.f / (1.f + __expf(-v)); }
DEVINL bf16x8 asbf(i32x4 v) { return __builtin_bit_cast(bf16x8, v); }

// ---- coherent-bypass (sc0|sc1) primitives: no cache invalidate/writeback ----
DEVINL void bypass_store_u16(void* p, uint32_t v) {
  asm volatile("global_store_short %0, %1, off sc0 sc1" :: "v"(p), "v"(v) : "memory");
}
// data-complete fence, then publish flag (bypass store)
DEVINL void flag_store(uint32_t* p, uint32_t v) {
  asm volatile("s_waitcnt vmcnt(0) lgkmcnt(0)\n\t"
               "global_store_dword %0, %1, off sc0 sc1"
               :: "v"(p), "v"(v) : "memory");
}
// all 64 lanes poll 64 slots until every slot >= target
DEVINL void poll_all_ge(const uint32_t* slots, uint32_t target) {
  const uint32_t* p = slots + (threadIdx.x & 63);
  for (;;) {
    uint32_t v;
    asm volatile("global_load_dword %0, %1, off sc0 sc1\n\t"
                 "s_waitcnt vmcnt(0)"
                 : "=v"(v) : "v"(p) : "memory");
    if (__all((int)(v >= target))) break;
  }
  __builtin_amdgcn_sched_barrier(0);
}
// batched 16B bypass loads with immediate offsets; caller fences once
#define GLD16(dst, ptr, imm) \
  asm volatile("global_load_dwordx4 %0, %1, off offset:" imm " sc0 sc1" \
               : "=v"(dst) : "v"(ptr))
#define GLD_ALL16(arr, ptr) do { \
  GLD16(arr[0],  ptr, "0");   GLD16(arr[1],  ptr, "64");  \
  GLD16(arr[2],  ptr, "128"); GLD16(arr[3],  ptr, "192"); \
  GLD16(arr[4],  ptr, "256"); GLD16(arr[5],  ptr, "320"); \
  GLD16(arr[6],  ptr, "384"); GLD16(arr[7],  ptr, "448"); \
  GLD16(arr[8],  ptr, "512"); GLD16(arr[9],  ptr, "576"); \
  GLD16(arr[10], ptr, "640"); GLD16(arr[11], ptr, "704"); \
  GLD16(arr[12], ptr, "768"); GLD16(arr[13], ptr, "832"); \
  GLD16(arr[14], ptr, "896"); GLD16(arr[15], ptr, "960"); \
  asm volatile("s_waitcnt vmcnt(0)" ::: "memory"); \
  __builtin_amdgcn_sched_barrier(0); \
} while (0)

#define MFMA(a, b, c) __builtin_amdgcn_mfma_f32_16x16x32_bf16((a), (b), (c), 0, 0, 0)

__global__ void __launch_bounds__(256, 1) init_ys_kernel(float* out, const float* bo2) {
  int i = blockIdx.x * 256 + threadIdx.x;
  if (i < BATCH * SEQ) out[i] = bo2[0];
}

__global__ void __launch_bounds__(256, 1) gru_persist(
    const float* __restrict__ x,  const float* __restrict__ Wg, const float* __restrict__ bg,
    const float* __restrict__ Wh, const float* __restrict__ bh,
    const float* __restrict__ Wo1,const float* __restrict__ bo1,
    const float* __restrict__ Wo2,const float* __restrict__ bo2,
    float* __restrict__ out, char* __restrict__ ws)
{
  extern __shared__ char smem[];
  const int bid  = blockIdx.x;
  const int gi   = bid & 7;        // group (presumed XCD-local; perf-only assumption)
  const int j    = bid >> 3;       // 0..31 within group
  const int tid  = threadIdx.x;
  const int lane = tid & 63;
  const int wave = tid >> 6;       // 0..3
  const int rowbase = gi * RPG;
  const int colbase = j * CPW;

  uint32_t* flagA = (uint32_t*)(ws + FLAGA_OFF) + gi * 64;
  uint32_t* flagB = (uint32_t*)(ws + FLAGB_OFF) + gi * 64;
  short* hbf  = (short*)(ws + HBF_OFF);
  short* rhbf = (short*)(ws + RHBF_OFF);

  // ---------------- init: weights -> LDS, h32 -> 0 ----------------
  for (int it = 0; it < 128; ++it) {
    int c = tid & 31;
    int k = (tid >> 5) + it * 8;
    int cg = (c < 16) ? (colbase + c) : (512 + colbase + (c - 16));
    *(short*)(smem + wgs_off(c, k)) = f2bf(Wg[(size_t)k * 1024 + cg]);
  }
  for (int it = 0; it < 64; ++it) {
    int c = tid & 15;
    int k = (tid >> 4) + it * 16;
    *(short*)(smem + whs_off(c, k)) = f2bf(Wh[(size_t)k * 512 + colbase + c]);
  }
  for (int it = 0; it < 32; ++it) {
    int c = tid & 15;
    int k = (tid >> 4) + it * 16;
    *(short*)(smem + wo1_off(c, k)) = (c < 8) ? f2bf(Wo1[(size_t)k * 256 + j * 8 + c]) : (short)0;
  }
  for (int idx = tid; idx < 32 * 17; idx += 256)
    *(float*)(smem + H32_OFF + idx * 4) = 0.f;

  const int lc = lane & 15;
  const float bgu  = bg[colbase + lc];
  const float bgr  = bg[512 + colbase + lc];
  const float bhc  = bh[colbase + lc];
  const float bo1c = (lc < 8) ? bo1[j * 8 + lc] : 0.f;
  const float wo2c = (lc < 8) ? Wo2[j * 8 + lc] : 0.f;
  __syncthreads();   // the ONLY block barrier

  const int mt   = wave & 1;                  // M-tile (rows 16*mt..)
  const int ctile= wave >> 1;                 // 0 = update/h-owner, 1 = reset/head
  const int arow = mt * 16 + lc;              // A-frag row (local)
  const int kl   = (lane >> 4) * 8;           // frag k sub-offset
  const int slot = j * 2 + mt;

  // per-wave fragment base pointers into the exchange buffers
  const char* hfrag_base  = (const char*)(hbf  + (size_t)(rowbase + arow) * HDIM + kl);
  const char* rhfrag_base = (const char*)(rhbf + (size_t)(rowbase + arow) * HDIM + kl);

  if (ctile == 0) {
    // =========== h-owner wave: update gate + candidate + h update ===========
    float hreg[4] = {0.f, 0.f, 0.f, 0.f};   // fp32 h master (wave-private copy)
    for (int t = 0; t < SEQ; ++t) {
      // x A-frags (plain cached loads; group-shared rows -> L2-resident)
      bf16x8 xa[16];
      {
        const float* xrow = x + ((size_t)(rowbase + arow) * SEQ + t) * IDIM + kl;
#pragma unroll
        for (int ks = 0; ks < 16; ++ks) {
          float4 a = *(const float4*)(xrow + ks * 32);
          float4 b = *(const float4*)(xrow + ks * 32 + 4);
          bf16x8 v;
          v[0] = f2bf(a.x); v[1] = f2bf(a.y); v[2] = f2bf(a.z); v[3] = f2bf(a.w);
          v[4] = f2bf(b.x); v[5] = f2bf(b.y); v[6] = f2bf(b.z); v[7] = f2bf(b.w);
          xa[ks] = v;
        }
      }
      // gates-x (update cols) + cand-x : no h dependence, overlap the waits
      f32x4 g0 = {0.f,0.f,0.f,0.f}, g1 = {0.f,0.f,0.f,0.f};
      f32x4 c0 = {0.f,0.f,0.f,0.f}, c1 = {0.f,0.f,0.f,0.f};
#pragma unroll
      for (int ks = 0; ks < 16; ks += 2) {
        g0 = MFMA(xa[ks],   *(const bf16x8*)(smem + wgs_off(lc, ks * 32 + kl)),       g0);
        g1 = MFMA(xa[ks+1], *(const bf16x8*)(smem + wgs_off(lc, (ks + 1) * 32 + kl)), g1);
        c0 = MFMA(xa[ks],   *(const bf16x8*)(smem + whs_off(lc, ks * 32 + kl)),       c0);
        c1 = MFMA(xa[ks+1], *(const bf16x8*)(smem + whs_off(lc, (ks + 1) * 32 + kl)), c1);
      }
      if (t) {
        poll_all_ge(flagB, (uint32_t)t);           // h_{t-1} published by all
        i32x4 ha[16];
        GLD_ALL16(ha, hfrag_base);
#pragma unroll
        for (int ks = 0; ks < 16; ks += 2) {
          g0 = MFMA(asbf(ha[ks]),   *(const bf16x8*)(smem + wgs_off(lc, 512 + ks * 32 + kl)),       g0);
          g1 = MFMA(asbf(ha[ks+1]), *(const bf16x8*)(smem + wgs_off(lc, 512 + (ks + 1) * 32 + kl)), g1);
        }
      }
      f32x4 g = g0 + g1;
      float uv[4];
#pragma unroll
      for (int ri = 0; ri < 4; ++ri) uv[ri] = sigm(g[ri] + bgu);

      if (t) {
        poll_all_ge(flagA, (uint32_t)(t + 1));     // rh(t) published by all
        i32x4 ra[16];
        GLD_ALL16(ra, rhfrag_base);
#pragma unroll
        for (int ks = 0; ks < 16; ks += 2) {
          c0 = MFMA(asbf(ra[ks]),   *(const bf16x8*)(smem + whs_off(lc, 512 + ks * 32 + kl)),       c0);
          c1 = MFMA(asbf(ra[ks+1]), *(const bf16x8*)(smem + whs_off(lc, 512 + (ks + 1) * 32 + kl)), c1);
        }
      }
      f32x4 cc = c0 + c1;
#pragma unroll
      for (int ri = 0; ri < 4; ++ri) {
        float cand = tanhf(cc[ri] + bhc);
        float hnew = hreg[ri] + uv[ri] * (cand - hreg[ri]);
        hreg[ri] = hnew;
        int row = mt * 16 + (lane >> 4) * 4 + ri;
        *(float*)(smem + h32_off(row, lc)) = hnew;                 // for ctile1's r*h
        bypass_store_u16(hbf + (size_t)(rowbase + row) * HDIM + colbase + lc,
                         (uint32_t)(uint16_t)f2bf(hnew));
        if (t == SEQ - 1)
          out[(size_t)(BATCH * SEQ) + (size_t)(rowbase + row) * HDIM + colbase + lc] = hnew;
      }
      flag_store(&flagB[slot], (uint32_t)(t + 1));
    }
  } else {
    // =========== reset/head wave: reset gate -> r*h publish; y head ===========
    for (int t = 0; t < SEQ; ++t) {
      bf16x8 xa[16];
      {
        const float* xrow = x + ((size_t)(rowbase + arow) * SEQ + t) * IDIM + kl;
#pragma unroll
        for (int ks = 0; ks < 16; ++ks) {
          float4 a = *(const float4*)(xrow + ks * 32);
          float4 b = *(const float4*)(xrow + ks * 32 + 4);
          bf16x8 v;
          v[0] = f2bf(a.x); v[1] = f2bf(a.y); v[2] = f2bf(a.z); v[3] = f2bf(a.w);
          v[4] = f2bf(b.x); v[5] = f2bf(b.y); v[6] = f2bf(b.z); v[7] = f2bf(b.w);
          xa[ks] = v;
        }
      }
      f32x4 g0 = {0.f,0.f,0.f,0.f}, g1 = {0.f,0.f,0.f,0.f};
#pragma unroll
      for (int ks = 0; ks < 16; ks += 2) {
        g0 = MFMA(xa[ks],   *(const bf16x8*)(smem + wgs_off(16 + lc, ks * 32 + kl)),       g0);
        g1 = MFMA(xa[ks+1], *(const bf16x8*)(smem + wgs_off(16 + lc, (ks + 1) * 32 + kl)), g1);
      }
      i32x4 ha[16];
      if (t) {
        poll_all_ge(flagB, (uint32_t)t);
        GLD_ALL16(ha, hfrag_base);
#pragma unroll
        for (int ks = 0; ks < 16; ks += 2) {
          g0 = MFMA(asbf(ha[ks]),   *(const bf16x8*)(smem + wgs_off(16 + lc, 512 + ks * 32 + kl)),       g0);
          g1 = MFMA(asbf(ha[ks+1]), *(const bf16x8*)(smem + wgs_off(16 + lc, 512 + (ks + 1) * 32 + kl)), g1);
        }
      }
      f32x4 g = g0 + g1;
#pragma unroll
      for (int ri = 0; ri < 4; ++ri) {
        int row = mt * 16 + (lane >> 4) * 4 + ri;
        float r = sigm(g[ri] + bgr);
        float hold = *(const float*)(smem + h32_off(row, lc));    // h_{t-1} (fp32)
        bypass_store_u16(rhbf + (size_t)(rowbase + row) * HDIM + colbase + lc,
                         (uint32_t)(uint16_t)f2bf(r * hold));
      }
      flag_store(&flagA[slot], (uint32_t)(t + 1));

      // head for y_{t-1} off the critical path (reuses ha = h_{t-1})
      if (t) {
        f32x4 d0 = {0.f,0.f,0.f,0.f}, d1 = {0.f,0.f,0.f,0.f};
#pragma unroll
        for (int ks = 0; ks < 16; ks += 2) {
          d0 = MFMA(asbf(ha[ks]),   *(const bf16x8*)(smem + wo1_off(lc, ks * 32 + kl)),       d0);
          d1 = MFMA(asbf(ha[ks+1]), *(const bf16x8*)(smem + wo1_off(lc, (ks + 1) * 32 + kl)), d1);
        }
        f32x4 d = d0 + d1;
#pragma unroll
        for (int ri = 0; ri < 4; ++ri) {
          float z = fmaxf(d[ri] + bo1c, 0.f) * wo2c;
          z += __shfl_xor(z, 1); z += __shfl_xor(z, 2);
          z += __shfl_xor(z, 4); z += __shfl_xor(z, 8);
          if (lc == 0) {
            int row = rowbase + mt * 16 + (lane >> 4) * 4 + ri;
            unsafeAtomicAdd(&out[(size_t)row * SEQ + (t - 1)], z);
          }
        }
      }
    }
    // epilogue: y_{SEQ-1} from h_{SEQ-1}
    poll_all_ge(flagB, (uint32_t)SEQ);
    i32x4 ha[16];
    GLD_ALL16(ha, hfrag_base);
    f32x4 d0 = {0.f,0.f,0.f,0.f}, d1 = {0.f,0.f,0.f,0.f};
#pragma unroll
    for (int ks = 0; ks < 16; ks += 2) {
      d0 = MFMA(asbf(ha[ks]),   *(const bf16x8*)(smem + wo1_off(lc, ks * 32 + kl)),       d0);
      d1 = MFMA(asbf(ha[ks+1]), *(const bf16x8*)(smem + wo1_off(lc, (ks + 1) * 32 + kl)), d1);
    }
    f32x4 d = d0 + d1;
#pragma unroll
    for (int ri = 0; ri < 4; ++ri) {
      float z = fmaxf(d[ri] + bo1c, 0.f) * wo2c;
      z += __shfl_xor(z, 1); z += __shfl_xor(z, 2);
      z += __shfl_xor(z, 4); z += __shfl_xor(z, 8);
      if (lc == 0) {
        int row = rowbase + mt * 16 + (lane >> 4) * 4 + ri;
        unsafeAtomicAdd(&out[(size_t)row * SEQ + (SEQ - 1)], z);
      }
    }
  }
}

extern "C" void kernel_launch(void* const* d_in, const int* in_sizes, int n_in,
                              void* d_out, int out_size, void* d_ws, size_t ws_size,
                              hipStream_t stream) {
  const float* x   = (const float*)d_in[0];
  const float* Wg  = (const float*)d_in[1];
  const float* bg  = (const float*)d_in[2];
  const float* Wh  = (const float*)d_in[3];
  const float* bh  = (const float*)d_in[4];
  const float* Wo1 = (const float*)d_in[5];
  const float* bo1 = (const float*)d_in[6];
  const float* Wo2 = (const float*)d_in[7];
  const float* bo2 = (const float*)d_in[8];
  float* out = (float*)d_out;
  char*  ws  = (char*)d_ws;
  if (ws_size < WS_NEEDED) return;

  // zero ONLY the flag arrays (4KB); hbf/rhbf need no init (t=0 never reads them)
  hipMemsetAsync(ws, 0, WS_ZERO, stream);
  // ys := bo2 (head partials accumulate on top)
  init_ys_kernel<<<dim3(512), dim3(256), 0, stream>>>(out, bo2);

  (void)hipFuncSetAttribute((const void*)gru_persist,
                            hipFuncAttributeMaxDynamicSharedMemorySize, SMEM_BYTES);

  // 256 blocks x ~114KB LDS -> exactly 1 block/CU, all co-resident.
  gru_persist<<<dim3(NG * WC), dim3(256), SMEM_BYTES, stream>>>(
      x, Wg, bg, Wh, bh, Wo1, bo1, Wo2, bo2, out, ws);
}

// Round 4
// 6024.231 us; speedup vs baseline: 3.0381x; 1.5118x over previous
//
#include <hip/hip_runtime.h>
#include <hip/hip_bf16.h>
#include <stdint.h>

typedef float f32x4 __attribute__((ext_vector_type(4)));
typedef short bf16x8 __attribute__((ext_vector_type(8)));
typedef int   i32x4  __attribute__((ext_vector_type(4)));

#define DEVINL static __device__ __forceinline__

// ---------------- problem dims ----------------
constexpr int BATCH = 256, SEQ = 512, IDIM = 512, HDIM = 512;
constexpr int NG  = 8;    // row groups; gi = bid & 7
constexpr int WC  = 32;   // wgs per group (column split)
constexpr int RPG = 32;   // batch rows per group
constexpr int CPW = 16;   // h-columns per wg

// ---------------- LDS map (bytes) ----------------
constexpr int WGS_OFF  = 0;        // Wg stripe [32 cols][1024 k] bf16 (64KB), XOR-swizzled
constexpr int WHS_OFF  = 65536;    // Wh stripe [16 cols][1024 k] bf16 (32KB)
constexpr int WO1_OFF  = 98304;    // Wo1 stripe [16 cols][512 k] bf16 (16KB, cols 8..15 zero)
constexpr int H32_OFF  = 114688;   // fp32 h master [32 rows][17 pad] (2176B)
constexpr int EPOCHB_OFF = 116864; // u32 epoch for flagB relay
constexpr int EPOCHA_OFF = 116928; // u32 epoch for flagA relay (64B apart)
constexpr int XPOSE_OFF  = 116992; // 4 waves x 16 rows x 40B = 2560B repack buffers
constexpr int SMEM_BYTES = XPOSE_OFF + 4 * 16 * 40;   // 119552

// ---------------- ws map (bytes) ----------------
// per-group 4KB flag region: flagA[64] at +0, flagB[64] at +1024
constexpr size_t FLAGS_BYTES = 32768;                 // 8 groups x 4KB
constexpr size_t HBF_OFF   = FLAGS_BYTES;             // bf16 h   [256][512] (256KB)
constexpr size_t RHBF_OFF  = HBF_OFF + 262144;        // bf16 r*h [256][512] (256KB)
constexpr size_t WS_NEEDED = RHBF_OFF + 262144;
constexpr size_t WS_ZERO   = FLAGS_BYTES;             // only flags get memset

DEVINL short f2bf(float f) {
  uint32_t u = __float_as_uint(f);
  u += 0x7FFFu + ((u >> 16) & 1u);   // RNE
  return (short)(u >> 16);
}
DEVINL int wgs_off(int c, int k) { return WGS_OFF + c * 2048 + ((k * 2) ^ ((c & 7) << 4)); }
DEVINL int whs_off(int c, int k) { return WHS_OFF + c * 2048 + ((k * 2) ^ ((c & 7) << 4)); }
DEVINL int wo1_off(int c, int k) { return WO1_OFF + c * 1024 + ((k * 2) ^ ((c & 7) << 4)); }
DEVINL int h32_off(int row, int c) { return H32_OFF + (row * 17 + c) * 4; }
DEVINL float sigm(float v) { return 1.f / (1.f + __expf(-v)); }
DEVINL bf16x8 asbf(i32x4 v) { return __builtin_bit_cast(bf16x8, v); }

// ---- coherent-bypass (sc0|sc1) primitives ----
// data-complete fence, then publish flag (bypass store)
DEVINL void flag_store(uint32_t* p, uint32_t v) {
  asm volatile("s_waitcnt vmcnt(0) lgkmcnt(0)\n\t"
               "global_store_dword %0, %1, off sc0 sc1"
               :: "v"(p), "v"(v) : "memory");
}
// 16-lane dwordx4 poll over 64 slots (4 cache lines), throttled
DEVINL void fabric_poll16(const uint32_t* slots, uint32_t target) {
  const uint32_t* p = slots + (threadIdx.x & 15) * 4;
  for (;;) {
    i32x4 v;
    asm volatile("global_load_dwordx4 %0, %1, off sc0 sc1\n\t"
                 "s_waitcnt vmcnt(0)"
                 : "=v"(v) : "v"(p) : "memory");
    uint32_t m0 = (uint32_t)v[0] < (uint32_t)v[1] ? (uint32_t)v[0] : (uint32_t)v[1];
    uint32_t m1 = (uint32_t)v[2] < (uint32_t)v[3] ? (uint32_t)v[2] : (uint32_t)v[3];
    uint32_t m  = m0 < m1 ? m0 : m1;
    if (__all((int)(m >= target))) break;
    __builtin_amdgcn_s_sleep(1);
  }
  __builtin_amdgcn_sched_barrier(0);
}
// LDS epoch relay
DEVINL void epoch_write(char* smem, int off, uint32_t v) {
  uint32_t a = (uint32_t)(uintptr_t)(smem + off);
  asm volatile("ds_write_b32 %0, %1" :: "v"(a), "v"(v) : "memory");
}
DEVINL void epoch_spin(char* smem, int off, uint32_t target) {
  uint32_t a = (uint32_t)(uintptr_t)(smem + off);
  for (;;) {
    uint32_t v;
    asm volatile("ds_read_b32 %0, %1\n\ts_waitcnt lgkmcnt(0)"
                 : "=v"(v) : "v"(a) : "memory");
    if (v >= target) break;
  }
  __builtin_amdgcn_sched_barrier(0);
}
// repack 16x16 bf16 tile through private LDS slice -> 8B/lane coalesced bypass store
DEVINL void coalesced_publish(char* smem, int xpose, short* dst_base,
                              int grow_base, int colbase, int lane,
                              const float* vals /*4*/) {
  const int q = lane >> 4, lc = lane & 15;
#pragma unroll
  for (int ri = 0; ri < 4; ++ri)
    *(short*)(smem + xpose + (q * 4 + ri) * 40 + lc * 2) = f2bf(vals[ri]);
  asm volatile("s_waitcnt lgkmcnt(0)" ::: "memory");
  __builtin_amdgcn_sched_barrier(0);
  const int rl = lane >> 2, cq = lane & 3;
  unsigned long long d = *(const unsigned long long*)(smem + xpose + rl * 40 + cq * 8);
  short* gp = dst_base + (size_t)(grow_base + rl) * HDIM + colbase + cq * 4;
  asm volatile("global_store_dwordx2 %0, %1, off sc0 sc1" :: "v"(gp), "v"(d) : "memory");
}
// batched 16B bypass loads; one fence
#define GLD16(dst, ptr, imm) \
  asm volatile("global_load_dwordx4 %0, %1, off offset:" imm " sc0 sc1" \
               : "=v"(dst) : "v"(ptr))
#define GLD_ALL16(arr, ptr) do { \
  GLD16(arr[0],  ptr, "0");   GLD16(arr[1],  ptr, "64");  \
  GLD16(arr[2],  ptr, "128"); GLD16(arr[3],  ptr, "192"); \
  GLD16(arr[4],  ptr, "256"); GLD16(arr[5],  ptr, "320"); \
  GLD16(arr[6],  ptr, "384"); GLD16(arr[7],  ptr, "448"); \
  GLD16(arr[8],  ptr, "512"); GLD16(arr[9],  ptr, "576"); \
  GLD16(arr[10], ptr, "640"); GLD16(arr[11], ptr, "704"); \
  GLD16(arr[12], ptr, "768"); GLD16(arr[13], ptr, "832"); \
  GLD16(arr[14], ptr, "896"); GLD16(arr[15], ptr, "960"); \
  asm volatile("s_waitcnt vmcnt(0)" ::: "memory"); \
  __builtin_amdgcn_sched_barrier(0); \
} while (0)

#define MFMA(a, b, c) __builtin_amdgcn_mfma_f32_16x16x32_bf16((a), (b), (c), 0, 0, 0)

__global__ void __launch_bounds__(256, 1) init_ys_kernel(float* out, const float* bo2) {
  int i = blockIdx.x * 256 + threadIdx.x;
  if (i < BATCH * SEQ) out[i] = bo2[0];
}

__global__ void __launch_bounds__(256, 1) gru_persist(
    const float* __restrict__ x,  const float* __restrict__ Wg, const float* __restrict__ bg,
    const float* __restrict__ Wh, const float* __restrict__ bh,
    const float* __restrict__ Wo1,const float* __restrict__ bo1,
    const float* __restrict__ Wo2,const float* __restrict__ bo2,
    float* __restrict__ out, char* __restrict__ ws)
{
  extern __shared__ char smem[];
  const int bid  = blockIdx.x;
  const int gi   = bid & 7;
  const int j    = bid >> 3;       // 0..31 within group
  const int tid  = threadIdx.x;
  const int lane = tid & 63;
  const int wave = tid >> 6;       // 0..3
  const int rowbase = gi * RPG;
  const int colbase = j * CPW;

  uint32_t* flagA = (uint32_t*)(ws + (size_t)gi * 4096);
  uint32_t* flagB = (uint32_t*)(ws + (size_t)gi * 4096 + 1024);
  short* hbf  = (short*)(ws + HBF_OFF);
  short* rhbf = (short*)(ws + RHBF_OFF);

  // ---------------- init: weights -> LDS, h32/epochs -> 0 ----------------
  for (int it = 0; it < 128; ++it) {
    int c = tid & 31;
    int k = (tid >> 5) + it * 8;
    int cg = (c < 16) ? (colbase + c) : (512 + colbase + (c - 16));
    *(short*)(smem + wgs_off(c, k)) = f2bf(Wg[(size_t)k * 1024 + cg]);
  }
  for (int it = 0; it < 64; ++it) {
    int c = tid & 15;
    int k = (tid >> 4) + it * 16;
    *(short*)(smem + whs_off(c, k)) = f2bf(Wh[(size_t)k * 512 + colbase + c]);
  }
  for (int it = 0; it < 32; ++it) {
    int c = tid & 15;
    int k = (tid >> 4) + it * 16;
    *(short*)(smem + wo1_off(c, k)) = (c < 8) ? f2bf(Wo1[(size_t)k * 256 + j * 8 + c]) : (short)0;
  }
  for (int idx = tid; idx < 32 * 17; idx += 256)
    *(float*)(smem + H32_OFF + idx * 4) = 0.f;
  if (tid == 0) {
    *(uint32_t*)(smem + EPOCHB_OFF) = 0u;
    *(uint32_t*)(smem + EPOCHA_OFF) = 0u;
  }

  const int lc = lane & 15;
  const float bgu  = bg[colbase + lc];
  const float bgr  = bg[512 + colbase + lc];
  const float bhc  = bh[colbase + lc];
  const float bo1c = (lc < 8) ? bo1[j * 8 + lc] : 0.f;
  const float wo2c = (lc < 8) ? Wo2[j * 8 + lc] : 0.f;
  __syncthreads();   // the ONLY block barrier

  const int mt    = wave & 1;                 // M-tile (rows 16*mt..)
  const int ctile = wave >> 1;                // 0 = update/h-owner, 1 = reset/head
  const int arow  = mt * 16 + lc;             // A-frag row (local)
  const int kl    = (lane >> 4) * 8;          // frag k sub-offset
  const int slot  = j * 2 + mt;
  const int xpose = XPOSE_OFF + wave * 640;
  const int grow  = rowbase + mt * 16;        // global row base of this wave's tile

  const char* hfrag_base  = (const char*)(hbf  + (size_t)(rowbase + arow) * HDIM + kl);
  const char* rhfrag_base = (const char*)(rhbf + (size_t)(rowbase + arow) * HDIM + kl);

  if (ctile == 0) {
    // =========== h-owner wave: update gate + candidate + h update ===========
    // wave0 = fabric poller for flagA; wave1 spins LDS epochA
    float hreg[4] = {0.f, 0.f, 0.f, 0.f};
    for (int t = 0; t < SEQ; ++t) {
      bf16x8 xa[16];
      {
        const float* xrow = x + ((size_t)(rowbase + arow) * SEQ + t) * IDIM + kl;
#pragma unroll
        for (int ks = 0; ks < 16; ++ks) {
          float4 a = *(const float4*)(xrow + ks * 32);
          float4 b = *(const float4*)(xrow + ks * 32 + 4);
          bf16x8 v;
          v[0] = f2bf(a.x); v[1] = f2bf(a.y); v[2] = f2bf(a.z); v[3] = f2bf(a.w);
          v[4] = f2bf(b.x); v[5] = f2bf(b.y); v[6] = f2bf(b.z); v[7] = f2bf(b.w);
          xa[ks] = v;
        }
      }
      f32x4 g0 = {0.f,0.f,0.f,0.f}, g1 = {0.f,0.f,0.f,0.f};
      f32x4 c0 = {0.f,0.f,0.f,0.f}, c1 = {0.f,0.f,0.f,0.f};
#pragma unroll
      for (int ks = 0; ks < 16; ks += 2) {
        g0 = MFMA(xa[ks],   *(const bf16x8*)(smem + wgs_off(lc, ks * 32 + kl)),       g0);
        g1 = MFMA(xa[ks+1], *(const bf16x8*)(smem + wgs_off(lc, (ks + 1) * 32 + kl)), g1);
        c0 = MFMA(xa[ks],   *(const bf16x8*)(smem + whs_off(lc, ks * 32 + kl)),       c0);
        c1 = MFMA(xa[ks+1], *(const bf16x8*)(smem + whs_off(lc, (ks + 1) * 32 + kl)), c1);
      }
      if (t) {
        epoch_spin(smem, EPOCHB_OFF, (uint32_t)t);     // h_{t-1} ready (relayed)
        i32x4 ha[16];
        GLD_ALL16(ha, hfrag_base);
#pragma unroll
        for (int ks = 0; ks < 16; ks += 2) {
          g0 = MFMA(asbf(ha[ks]),   *(const bf16x8*)(smem + wgs_off(lc, 512 + ks * 32 + kl)),       g0);
          g1 = MFMA(asbf(ha[ks+1]), *(const bf16x8*)(smem + wgs_off(lc, 512 + (ks + 1) * 32 + kl)), g1);
        }
      }
      f32x4 g = g0 + g1;
      float uv[4];
#pragma unroll
      for (int ri = 0; ri < 4; ++ri) uv[ri] = sigm(g[ri] + bgu);

      // rh(t) ready?
      if (wave == 0) {
        fabric_poll16(flagA, (uint32_t)(t + 1));
        epoch_write(smem, EPOCHA_OFF, (uint32_t)(t + 1));
      } else {
        epoch_spin(smem, EPOCHA_OFF, (uint32_t)(t + 1));
      }
      {
        i32x4 ra[16];
        GLD_ALL16(ra, rhfrag_base);
#pragma unroll
        for (int ks = 0; ks < 16; ks += 2) {
          c0 = MFMA(asbf(ra[ks]),   *(const bf16x8*)(smem + whs_off(lc, 512 + ks * 32 + kl)),       c0);
          c1 = MFMA(asbf(ra[ks+1]), *(const bf16x8*)(smem + whs_off(lc, 512 + (ks + 1) * 32 + kl)), c1);
        }
      }
      f32x4 cc = c0 + c1;
      float hnv[4];
#pragma unroll
      for (int ri = 0; ri < 4; ++ri) {
        float cand = tanhf(cc[ri] + bhc);
        float hnew = hreg[ri] + uv[ri] * (cand - hreg[ri]);
        hreg[ri] = hnew;
        hnv[ri] = hnew;
        int row = mt * 16 + (lane >> 4) * 4 + ri;
        *(float*)(smem + h32_off(row, lc)) = hnew;     // for ctile1's r*h next step
        if (t == SEQ - 1)
          out[(size_t)(BATCH * SEQ) + (size_t)(rowbase + row) * HDIM + colbase + lc] = hnew;
      }
      coalesced_publish(smem, xpose, hbf, grow, colbase, lane, hnv);
      flag_store(&flagB[slot], (uint32_t)(t + 1));
    }
  } else {
    // =========== reset/head wave: reset gate -> r*h publish; y head ===========
    // wave2 = fabric poller for flagB; wave3 spins LDS epochB
    for (int t = 0; t < SEQ; ++t) {
      bf16x8 xa[16];
      {
        const float* xrow = x + ((size_t)(rowbase + arow) * SEQ + t) * IDIM + kl;
#pragma unroll
        for (int ks = 0; ks < 16; ++ks) {
          float4 a = *(const float4*)(xrow + ks * 32);
          float4 b = *(const float4*)(xrow + ks * 32 + 4);
          bf16x8 v;
          v[0] = f2bf(a.x); v[1] = f2bf(a.y); v[2] = f2bf(a.z); v[3] = f2bf(a.w);
          v[4] = f2bf(b.x); v[5] = f2bf(b.y); v[6] = f2bf(b.z); v[7] = f2bf(b.w);
          xa[ks] = v;
        }
      }
      f32x4 g0 = {0.f,0.f,0.f,0.f}, g1 = {0.f,0.f,0.f,0.f};
#pragma unroll
      for (int ks = 0; ks < 16; ks += 2) {
        g0 = MFMA(xa[ks],   *(const bf16x8*)(smem + wgs_off(16 + lc, ks * 32 + kl)),       g0);
        g1 = MFMA(xa[ks+1], *(const bf16x8*)(smem + wgs_off(16 + lc, (ks + 1) * 32 + kl)), g1);
      }
      i32x4 ha[16];
      if (t) {
        if (wave == 2) {
          fabric_poll16(flagB, (uint32_t)t);
          epoch_write(smem, EPOCHB_OFF, (uint32_t)t);
        } else {
          epoch_spin(smem, EPOCHB_OFF, (uint32_t)t);
        }
        GLD_ALL16(ha, hfrag_base);
#pragma unroll
        for (int ks = 0; ks < 16; ks += 2) {
          g0 = MFMA(asbf(ha[ks]),   *(const bf16x8*)(smem + wgs_off(16 + lc, 512 + ks * 32 + kl)),       g0);
          g1 = MFMA(asbf(ha[ks+1]), *(const bf16x8*)(smem + wgs_off(16 + lc, 512 + (ks + 1) * 32 + kl)), g1);
        }
      }
      f32x4 g = g0 + g1;
      float rhv[4];
#pragma unroll
      for (int ri = 0; ri < 4; ++ri) {
        int row = mt * 16 + (lane >> 4) * 4 + ri;
        float r = sigm(g[ri] + bgr);
        float hold = *(const float*)(smem + h32_off(row, lc));    // h_{t-1} fp32
        rhv[ri] = r * hold;
      }
      coalesced_publish(smem, xpose, rhbf, grow, colbase, lane, rhv);
      flag_store(&flagA[slot], (uint32_t)(t + 1));

      // head for y_{t-1}, off the critical path (uses ha = h_{t-1})
      if (t) {
        f32x4 d0 = {0.f,0.f,0.f,0.f}, d1 = {0.f,0.f,0.f,0.f};
#pragma unroll
        for (int ks = 0; ks < 16; ks += 2) {
          d0 = MFMA(asbf(ha[ks]),   *(const bf16x8*)(smem + wo1_off(lc, ks * 32 + kl)),       d0);
          d1 = MFMA(asbf(ha[ks+1]), *(const bf16x8*)(smem + wo1_off(lc, (ks + 1) * 32 + kl)), d1);
        }
        f32x4 d = d0 + d1;
#pragma unroll
        for (int ri = 0; ri < 4; ++ri) {
          float z = fmaxf(d[ri] + bo1c, 0.f) * wo2c;
          z += __shfl_xor(z, 1); z += __shfl_xor(z, 2);
          z += __shfl_xor(z, 4); z += __shfl_xor(z, 8);
          if (lc == 0) {
            int row = rowbase + mt * 16 + (lane >> 4) * 4 + ri;
            unsafeAtomicAdd(&out[(size_t)row * SEQ + (t - 1)], z);
          }
        }
      }
    }
    // epilogue: y_{SEQ-1} from h_{SEQ-1}
    if (wave == 2) {
      fabric_poll16(flagB, (uint32_t)SEQ);
      epoch_write(smem, EPOCHB_OFF, (uint32_t)SEQ);
    } else {
      epoch_spin(smem, EPOCHB_OFF, (uint32_t)SEQ);
    }
    i32x4 ha[16];
    GLD_ALL16(ha, hfrag_base);
    f32x4 d0 = {0.f,0.f,0.f,0.f}, d1 = {0.f,0.f,0.f,0.f};
#pragma unroll
    for (int ks = 0; ks < 16; ks += 2) {
      d0 = MFMA(asbf(ha[ks]),   *(const bf16x8*)(smem + wo1_off(lc, ks * 32 + kl)),       d0);
      d1 = MFMA(asbf(ha[ks+1]), *(const bf16x8*)(smem + wo1_off(lc, (ks + 1) * 32 + kl)), d1);
    }
    f32x4 d = d0 + d1;
#pragma unroll
    for (int ri = 0; ri < 4; ++ri) {
      float z = fmaxf(d[ri] + bo1c, 0.f) * wo2c;
      z += __shfl_xor(z, 1); z += __shfl_xor(z, 2);
      z += __shfl_xor(z, 4); z += __shfl_xor(z, 8);
      if (lc == 0) {
        int row = rowbase + mt * 16 + (lane >> 4) * 4 + ri;
        unsafeAtomicAdd(&out[(size_t)row * SEQ + (SEQ - 1)], z);
      }
    }
  }
}

extern "C" void kernel_launch(void* const* d_in, const int* in_sizes, int n_in,
                              void* d_out, int out_size, void* d_ws, size_t ws_size,
                              hipStream_t stream) {
  const float* x   = (const float*)d_in[0];
  const float* Wg  = (const float*)d_in[1];
  const float* bg  = (const float*)d_in[2];
  const float* Wh  = (const float*)d_in[3];
  const float* bh  = (const float*)d_in[4];
  const float* Wo1 = (const float*)d_in[5];
  const float* bo1 = (const float*)d_in[6];
  const float* Wo2 = (const float*)d_in[7];
  const float* bo2 = (const float*)d_in[8];
  float* out = (float*)d_out;
  char*  ws  = (char*)d_ws;
  if (ws_size < WS_NEEDED) return;

  hipMemsetAsync(ws, 0, WS_ZERO, stream);      // flags only
  init_ys_kernel<<<dim3(512), dim3(256), 0, stream>>>(out, bo2);

  (void)hipFuncSetAttribute((const void*)gru_persist,
                            hipFuncAttributeMaxDynamicSharedMemorySize, SMEM_BYTES);

  gru_persist<<<dim3(NG * WC), dim3(256), SMEM_BYTES, stream>>>(
      x, Wg, bg, Wh, bh, Wo1, bo1, Wo2, bo2, out, ws);
}

// Round 7
// 5355.093 us; speedup vs baseline: 3.4177x; 1.1250x over previous
//
#include <hip/hip_runtime.h>
#include <hip/hip_bf16.h>
#include <stdint.h>

typedef float f32x4 __attribute__((ext_vector_type(4)));
typedef short bf16x8 __attribute__((ext_vector_type(8)));
typedef int   i32x4  __attribute__((ext_vector_type(4)));

#define DEVINL static __device__ __forceinline__

// ---------------- problem dims ----------------
constexpr int BATCH = 256, SEQ = 512, IDIM = 512, HDIM = 512;
constexpr int NG = 8, WC = 32, RPG = 32, CPW = 16;

// ---------------- LDS map (bytes) ----------------
constexpr int WGS_OFF = 0;        // Wg stripe [32 cols][1024 k] bf16 (64KB), XOR-swizzled
constexpr int WHS_OFF = 65536;    // Wh stripe [16 cols][1024 k] bf16 (32KB)
constexpr int WO1_OFF = 98304;    // Wo1 stripe [16 cols][512 k] bf16 (16KB, cols 8..15 zero)
constexpr int XPOSE_OFF = 114688; // 2 waves x 640B repack buffers
constexpr int VERD_OFF  = 116032; // l2l verdict
constexpr int XR_OFF    = 116036; // packed (xcc<<8)|rank
constexpr int SMEM_BYTES = 116096;

// ---------------- ws map (bytes) ----------------
constexpr size_t CNT_OFF  = 0;     // u32[8] per-XCD block counts
constexpr size_t RDY_OFF  = 64;    // one-time barrier counter
constexpr size_t L2F_OFF = 1024;   // 8 groups x 512B: fA 64xu32 at +0, fB at +256 (sc1/L2 domain)
constexpr size_t L3F_OFF = 5120;   // same layout (sc0sc1/system domain, memset-zeroed)
constexpr size_t WS_ZERO = 9216;
constexpr size_t HBF_OFF  = 12288;            // bf16 h   [256][512] (256KB)
constexpr size_t RHBF_OFF = HBF_OFF + 262144; // bf16 r*h [256][512] (256KB)
constexpr size_t WS_NEEDED = RHBF_OFF + 262144;

DEVINL short f2bf(float f) {
  uint32_t u = __float_as_uint(f);
  u += 0x7FFFu + ((u >> 16) & 1u);   // RNE
  return (short)(u >> 16);
}
DEVINL int wgs_off(int c, int k) { return WGS_OFF + c * 2048 + ((k * 2) ^ ((c & 7) << 4)); }
DEVINL int whs_off(int c, int k) { return WHS_OFF + c * 2048 + ((k * 2) ^ ((c & 7) << 4)); }
DEVINL int wo1_off(int c, int k) { return WO1_OFF + c * 1024 + ((k * 2) ^ ((c & 7) << 4)); }
DEVINL float sigm(float v) { return 1.f / (1.f + __expf(-v)); }
DEVINL bf16x8 asbf(i32x4 v) { return __builtin_bit_cast(bf16x8, v); }
DEVINL uint64_t rtclock() {
  uint64_t t;
  asm volatile("s_memrealtime %0\n\ts_waitcnt lgkmcnt(0)" : "=s"(t));
  return t;
}

// ---------------- flag / exchange primitives ----------------
// L2L path: sc1 = device scope -> bypass L0/L1, meet in the XCD's L2.
// Fallback:  sc0 sc1 = system scope (round-3/4-proven).
template<bool L2L> DEVINL void flag_pub(uint32_t* p, uint32_t v) {
  if constexpr (L2L)
    asm volatile("s_waitcnt vmcnt(0) lgkmcnt(0)\n\tglobal_store_dword %0, %1, off sc1"
                 :: "v"(p), "v"(v) : "memory");
  else
    asm volatile("s_waitcnt vmcnt(0) lgkmcnt(0)\n\tglobal_store_dword %0, %1, off sc0 sc1"
                 :: "v"(p), "v"(v) : "memory");
}
// 64 lanes poll 64 u32 slots (4 cache lines). Bounded: converts any stale-flag
// pathology into a fast failing bench instead of a 600s timeout.
template<bool L2L> DEVINL void poll64(const uint32_t* slots, uint32_t target) {
  const uint32_t* p = slots + (threadIdx.x & 63);
  const int bound = L2L ? 20000 : 300000;
  int iter = 0;
  for (;;) {
    uint32_t v;
    if constexpr (L2L)
      asm volatile("global_load_dword %0, %1, off sc1\n\ts_waitcnt vmcnt(0)"
                   : "=v"(v) : "v"(p) : "memory");
    else
      asm volatile("global_load_dword %0, %1, off sc0 sc1\n\ts_waitcnt vmcnt(0)"
                   : "=v"(v) : "v"(p) : "memory");
    if (__all((int)(v >= target))) break;
    if (++iter > bound) break;
    if constexpr (!L2L) __builtin_amdgcn_s_sleep(1);
  }
  __builtin_amdgcn_sched_barrier(0);
}
// repack 16x16 bf16 tile through private LDS slice -> 8B/lane coalesced store
template<bool L2L>
DEVINL void publish16x16(char* smem, int xpose, short* dst, int grow, int colbase,
                         int lane, const float* vals) {
  const int q = lane >> 4, lc = lane & 15;
#pragma unroll
  for (int ri = 0; ri < 4; ++ri)
    *(short*)(smem + xpose + (q * 4 + ri) * 40 + lc * 2) = f2bf(vals[ri]);
  asm volatile("s_waitcnt lgkmcnt(0)" ::: "memory");
  __builtin_amdgcn_sched_barrier(0);
  const int rl = lane >> 2, cq = lane & 3;
  unsigned long long d = *(const unsigned long long*)(smem + xpose + rl * 40 + cq * 8);
  short* gp = dst + (size_t)(grow + rl) * HDIM + colbase + cq * 4;
  if constexpr (L2L)
    asm volatile("global_store_dwordx2 %0, %1, off sc1" :: "v"(gp), "v"(d) : "memory");
  else
    asm volatile("global_store_dwordx2 %0, %1, off sc0 sc1" :: "v"(gp), "v"(d) : "memory");
}
#define GLD16_(dst, ptr, imm, SC) \
  asm volatile("global_load_dwordx4 %0, %1, off offset:" imm " " SC : "=v"(dst) : "v"(ptr))
#define GLD_ALL16_(arr, ptr, SC) do { \
  GLD16_(arr[0],  ptr, "0",   SC); GLD16_(arr[1],  ptr, "64",  SC); \
  GLD16_(arr[2],  ptr, "128", SC); GLD16_(arr[3],  ptr, "192", SC); \
  GLD16_(arr[4],  ptr, "256", SC); GLD16_(arr[5],  ptr, "320", SC); \
  GLD16_(arr[6],  ptr, "384", SC); GLD16_(arr[7],  ptr, "448", SC); \
  GLD16_(arr[8],  ptr, "512", SC); GLD16_(arr[9],  ptr, "576", SC); \
  GLD16_(arr[10], ptr, "640", SC); GLD16_(arr[11], ptr, "704", SC); \
  GLD16_(arr[12], ptr, "768", SC); GLD16_(arr[13], ptr, "832", SC); \
  GLD16_(arr[14], ptr, "896", SC); GLD16_(arr[15], ptr, "960", SC); \
  asm volatile("s_waitcnt vmcnt(0)" ::: "memory"); \
  __builtin_amdgcn_sched_barrier(0); \
} while (0)
template<bool L2L> DEVINL void gld_frag16(i32x4* a, const char* p) {
  if constexpr (L2L) { GLD_ALL16_(a, p, "sc1"); } else { GLD_ALL16_(a, p, "sc0 sc1"); }
}

#define MFMA(a, b, c) __builtin_amdgcn_mfma_f32_16x16x32_bf16((a), (b), (c), 0, 0, 0)
#define LDB(off) (*(const bf16x8*)(smem + (off)))

__global__ void __launch_bounds__(256, 1) init_ys_kernel(float* out, const float* bo2) {
  int i = blockIdx.x * 256 + threadIdx.x;
  if (i < BATCH * SEQ) out[i] = bo2[0];
}

struct Ctx {
  const float* x; float* out; char* smem;
  const char *hfrag, *rhfrag;
  short *hbf, *rhbf;
  const uint32_t *fA, *fB;
  uint32_t *myA, *myB;
  int rowbase, colbase, arow, kl, lc, mt, lane, xpose, grow;
  float bgu, bgr, bhc, bo1c, wo2c;
};

template<bool L2L> DEVINL void run_loop(const Ctx& c) {
  char* smem = c.smem;
  float hreg[4] = {0.f, 0.f, 0.f, 0.f};
  for (int t = 0; t < SEQ; ++t) {
    // ---- x A-frags + x-part MFMAs (no cross-block dependence) ----
    bf16x8 xa[16];
    {
      const float* xrow = c.x + ((size_t)(c.rowbase + c.arow) * SEQ + t) * IDIM + c.kl;
#pragma unroll
      for (int ks = 0; ks < 16; ++ks) {
        float4 a = *(const float4*)(xrow + ks * 32);
        float4 b = *(const float4*)(xrow + ks * 32 + 4);
        bf16x8 v;
        v[0] = f2bf(a.x); v[1] = f2bf(a.y); v[2] = f2bf(a.z); v[3] = f2bf(a.w);
        v[4] = f2bf(b.x); v[5] = f2bf(b.y); v[6] = f2bf(b.z); v[7] = f2bf(b.w);
        xa[ks] = v;
      }
    }
    f32x4 gu0 = {0,0,0,0}, gu1 = {0,0,0,0}, gr0 = {0,0,0,0}, gr1 = {0,0,0,0};
    f32x4 cx0 = {0,0,0,0}, cx1 = {0,0,0,0};
#pragma unroll
    for (int ks = 0; ks < 16; ks += 2) {
      gu0 = MFMA(xa[ks],   LDB(wgs_off(c.lc, ks * 32 + c.kl)),            gu0);
      gu1 = MFMA(xa[ks+1], LDB(wgs_off(c.lc, (ks + 1) * 32 + c.kl)),      gu1);
      gr0 = MFMA(xa[ks],   LDB(wgs_off(16 + c.lc, ks * 32 + c.kl)),       gr0);
      gr1 = MFMA(xa[ks+1], LDB(wgs_off(16 + c.lc, (ks + 1) * 32 + c.kl)), gr1);
      cx0 = MFMA(xa[ks],   LDB(whs_off(c.lc, ks * 32 + c.kl)),            cx0);
      cx1 = MFMA(xa[ks+1], LDB(whs_off(c.lc, (ks + 1) * 32 + c.kl)),      cx1);
    }
    // ---- hop B: h_{t-1} ----
    i32x4 ha[16];
    if (t) {
      poll64<L2L>(c.fB, (uint32_t)t);
      gld_frag16<L2L>(ha, c.hfrag);
#pragma unroll
      for (int ks = 0; ks < 16; ks += 2) {
        gu0 = MFMA(asbf(ha[ks]),   LDB(wgs_off(c.lc, 512 + ks * 32 + c.kl)),            gu0);
        gu1 = MFMA(asbf(ha[ks+1]), LDB(wgs_off(c.lc, 512 + (ks + 1) * 32 + c.kl)),      gu1);
        gr0 = MFMA(asbf(ha[ks]),   LDB(wgs_off(16 + c.lc, 512 + ks * 32 + c.kl)),       gr0);
        gr1 = MFMA(asbf(ha[ks+1]), LDB(wgs_off(16 + c.lc, 512 + (ks + 1) * 32 + c.kl)), gr1);
      }
    }
    f32x4 gu = gu0 + gu1, gr = gr0 + gr1;
    float uv[4], rhv[4];
#pragma unroll
    for (int ri = 0; ri < 4; ++ri) {
      uv[ri]  = sigm(gu[ri] + c.bgu);
      rhv[ri] = sigm(gr[ri] + c.bgr) * hreg[ri];
    }
    if (t) {   // rh(0)=0 group-wide: skip publish/hop at t=0
      publish16x16<L2L>(smem, c.xpose, c.rhbf, c.grow, c.colbase, c.lane, rhv);
      flag_pub<L2L>(c.myA, (uint32_t)(t + 1));
    }
    // ---- head MFMAs in the fA shadow (h_{t-1} already in regs) ----
    f32x4 hd0 = {0,0,0,0}, hd1 = {0,0,0,0};
    if (t) {
#pragma unroll
      for (int ks = 0; ks < 16; ks += 2) {
        hd0 = MFMA(asbf(ha[ks]),   LDB(wo1_off(c.lc, ks * 32 + c.kl)),       hd0);
        hd1 = MFMA(asbf(ha[ks+1]), LDB(wo1_off(c.lc, (ks + 1) * 32 + c.kl)), hd1);
      }
    }
    // ---- hop A: r*h ----
    f32x4 ch0 = {0,0,0,0}, ch1 = {0,0,0,0};
    if (t) {
      poll64<L2L>(c.fA, (uint32_t)(t + 1));
      i32x4 ra[16];
      gld_frag16<L2L>(ra, c.rhfrag);
#pragma unroll
      for (int ks = 0; ks < 16; ks += 2) {
        ch0 = MFMA(asbf(ra[ks]),   LDB(whs_off(c.lc, 512 + ks * 32 + c.kl)),       ch0);
        ch1 = MFMA(asbf(ra[ks+1]), LDB(whs_off(c.lc, 512 + (ks + 1) * 32 + c.kl)), ch1);
      }
    }
    f32x4 cc = cx0 + cx1 + ch0 + ch1;
    float hnv[4];
#pragma unroll
    for (int ri = 0; ri < 4; ++ri) {
      float cand = tanhf(cc[ri] + c.bhc);
      float hnew = hreg[ri] + uv[ri] * (cand - hreg[ri]);
      hreg[ri] = hnew; hnv[ri] = hnew;
      if (t == SEQ - 1) {
        int row = c.mt * 16 + (c.lane >> 4) * 4 + ri;
        c.out[(size_t)(BATCH * SEQ) + (size_t)(c.rowbase + row) * HDIM + c.colbase + c.lc] = hnew;
      }
    }
    publish16x16<L2L>(smem, c.xpose, c.hbf, c.grow, c.colbase, c.lane, hnv);
    flag_pub<L2L>(c.myB, (uint32_t)(t + 1));
    // ---- finish head y_{t-1}; atomics AFTER fB pub (off the drain path) ----
    if (t) {
      f32x4 d = hd0 + hd1;
#pragma unroll
      for (int ri = 0; ri < 4; ++ri) {
        float z = fmaxf(d[ri] + c.bo1c, 0.f) * c.wo2c;
        z += __shfl_xor(z, 1); z += __shfl_xor(z, 2);
        z += __shfl_xor(z, 4); z += __shfl_xor(z, 8);
        if (c.lc == 0) {
          int row = c.rowbase + c.mt * 16 + (c.lane >> 4) * 4 + ri;
          unsafeAtomicAdd(&c.out[(size_t)row * SEQ + (t - 1)], z);
        }
      }
    }
  }
  // ---- epilogue: y_{SEQ-1} ----
  poll64<L2L>(c.fB, (uint32_t)SEQ);
  i32x4 ha[16];
  gld_frag16<L2L>(ha, c.hfrag);
  f32x4 hd0 = {0,0,0,0}, hd1 = {0,0,0,0};
#pragma unroll
  for (int ks = 0; ks < 16; ks += 2) {
    hd0 = MFMA(asbf(ha[ks]),   LDB(wo1_off(c.lc, ks * 32 + c.kl)),       hd0);
    hd1 = MFMA(asbf(ha[ks+1]), LDB(wo1_off(c.lc, (ks + 1) * 32 + c.kl)), hd1);
  }
  f32x4 d = hd0 + hd1;
#pragma unroll
  for (int ri = 0; ri < 4; ++ri) {
    float z = fmaxf(d[ri] + c.bo1c, 0.f) * c.wo2c;
    z += __shfl_xor(z, 1); z += __shfl_xor(z, 2);
    z += __shfl_xor(z, 4); z += __shfl_xor(z, 8);
    if (c.lc == 0) {
      int row = c.rowbase + c.mt * 16 + (c.lane >> 4) * 4 + ri;
      unsafeAtomicAdd(&c.out[(size_t)row * SEQ + (SEQ - 1)], z);
    }
  }
}

__global__ void __launch_bounds__(128, 1) gru_persist(
    const float* __restrict__ x,  const float* __restrict__ Wg, const float* __restrict__ bg,
    const float* __restrict__ Wh, const float* __restrict__ bh,
    const float* __restrict__ Wo1,const float* __restrict__ bo1,
    const float* __restrict__ Wo2,const float* __restrict__ bo2,
    float* __restrict__ out, char* __restrict__ ws)
{
  extern __shared__ char smem[];
  const int bid  = blockIdx.x;
  const int tid  = threadIdx.x;
  const int lane = tid & 63;
  const int wave = tid >> 6;       // 0,1 == mt

  // ---------- handshake (wave0): structural XCD grouping, bounded, no probe ----------
  if (wave == 0) {
    uint32_t myxcc = __builtin_amdgcn_s_getreg(63508) & 7u;   // HW_REG_XCC_ID
    uint32_t rank = 0;
    if (lane == 0)
      rank = __hip_atomic_fetch_add((uint32_t*)(ws + CNT_OFF) + myxcc, 1u,
                                    __ATOMIC_RELAXED, __HIP_MEMORY_SCOPE_AGENT);
    rank = (uint32_t)__shfl((int)rank, 0);
    // sc1 self-zero of own prospective L2 flag slots (kills replay-stale L2 lines)
    if (lane < 4) {
      char* p = ws + L2F_OFF + (size_t)myxcc * 512 + (size_t)(lane >> 1) * 256
                + (size_t)((rank & 31) * 2 + (lane & 1)) * 4;
      uint32_t z = 0;
      asm volatile("global_store_dword %0, %1, off sc1" :: "v"(p), "v"(z) : "memory");
    }
    asm volatile("s_waitcnt vmcnt(0)" ::: "memory");
    if (lane == 0)
      __hip_atomic_fetch_add((uint32_t*)(ws + RDY_OFF), 1u,
                             __ATOMIC_RELEASE, __HIP_MEMORY_SCOPE_AGENT);
    uint64_t t0 = rtclock();
    while (__hip_atomic_load((uint32_t*)(ws + RDY_OFF),
                             __ATOMIC_ACQUIRE, __HIP_MEMORY_SCOPE_AGENT) < 256u) {
      if (rtclock() - t0 > 2000000ull) break;   // ~20ms bound: cannot hang
      __builtin_amdgcn_s_sleep(16);
    }
    uint32_t cv = __hip_atomic_load((uint32_t*)(ws + CNT_OFF) + (lane & 7),
                                    __ATOMIC_RELAXED, __HIP_MEMORY_SCOPE_AGENT);
    int l2l = __all((int)(cv == 32u)) ? 1 : 0;   // groups == physical XCDs, 32 blocks each
    if (lane == 0) {
      *(int*)(smem + VERD_OFF) = l2l;
      *(uint32_t*)(smem + XR_OFF) = (myxcc << 8) | (rank & 255u);
    }
  }
  __syncthreads();

  const int l2l = *(const int*)(smem + VERD_OFF);
  const uint32_t xr = *(const uint32_t*)(smem + XR_OFF);
  const int gi = l2l ? (int)(xr >> 8) : (bid & 7);
  const int j  = l2l ? (int)(xr & 255u) : (bid >> 3);
  const int rowbase = gi * RPG;
  const int colbase = j * CPW;

  // ---------------- init: weights -> LDS (128 threads) ----------------
  for (int it = 0; it < 256; ++it) {
    int cc = tid & 31;
    int k = (tid >> 5) + it * 4;
    int cg = (cc < 16) ? (colbase + cc) : (512 + colbase + (cc - 16));
    *(short*)(smem + wgs_off(cc, k)) = f2bf(Wg[(size_t)k * 1024 + cg]);
  }
  for (int it = 0; it < 128; ++it) {
    int cc = tid & 15;
    int k = (tid >> 4) + it * 8;
    *(short*)(smem + whs_off(cc, k)) = f2bf(Wh[(size_t)k * 512 + colbase + cc]);
  }
  for (int it = 0; it < 64; ++it) {
    int cc = tid & 15;
    int k = (tid >> 4) + it * 8;
    *(short*)(smem + wo1_off(cc, k)) = (cc < 8) ? f2bf(Wo1[(size_t)k * 256 + j * 8 + cc]) : (short)0;
  }

  const int lc = lane & 15;
  Ctx c;
  c.x = x; c.out = out; c.smem = smem;
  c.bgu  = bg[colbase + lc];
  c.bgr  = bg[512 + colbase + lc];
  c.bhc  = bh[colbase + lc];
  c.bo1c = (lc < 8) ? bo1[j * 8 + lc] : 0.f;
  c.wo2c = (lc < 8) ? Wo2[j * 8 + lc] : 0.f;
  __syncthreads();

  c.rowbase = rowbase; c.colbase = colbase;
  c.mt = wave; c.lane = lane; c.lc = lc;
  c.arow = wave * 16 + lc;
  c.kl   = (lane >> 4) * 8;
  c.xpose = XPOSE_OFF + wave * 640;
  c.grow  = rowbase + wave * 16;
  c.hbf  = (short*)(ws + HBF_OFF);
  c.rhbf = (short*)(ws + RHBF_OFF);
  c.hfrag  = (const char*)(c.hbf  + (size_t)(rowbase + c.arow) * HDIM + c.kl);
  c.rhfrag = (const char*)(c.rhbf + (size_t)(rowbase + c.arow) * HDIM + c.kl);
  char* fgrp = ws + (l2l ? L2F_OFF : L3F_OFF) + (size_t)gi * 512;
  c.fA = (const uint32_t*)fgrp;
  c.fB = (const uint32_t*)(fgrp + 256);
  const int slot = j * 2 + wave;
  c.myA = (uint32_t*)(fgrp + (size_t)slot * 4);
  c.myB = (uint32_t*)(fgrp + 256 + (size_t)slot * 4);

  if (l2l) run_loop<true>(c); else run_loop<false>(c);
}

extern "C" void kernel_launch(void* const* d_in, const int* in_sizes, int n_in,
                              void* d_out, int out_size, void* d_ws, size_t ws_size,
                              hipStream_t stream) {
  const float* x   = (const float*)d_in[0];
  const float* Wg  = (const float*)d_in[1];
  const float* bg  = (const float*)d_in[2];
  const float* Wh  = (const float*)d_in[3];
  const float* bh  = (const float*)d_in[4];
  const float* Wo1 = (const float*)d_in[5];
  const float* bo1 = (const float*)d_in[6];
  const float* Wo2 = (const float*)d_in[7];
  const float* bo2 = (const float*)d_in[8];
  float* out = (float*)d_out;
  char*  ws  = (char*)d_ws;
  if (ws_size < WS_NEEDED) return;

  hipMemsetAsync(ws, 0, WS_ZERO, stream);      // counters + both flag regions
  init_ys_kernel<<<dim3(512), dim3(256), 0, stream>>>(out, bo2);

  (void)hipFuncSetAttribute((const void*)gru_persist,
                            hipFuncAttributeMaxDynamicSharedMemorySize, SMEM_BYTES);

  // 256 blocks x ~113KB LDS -> 1 block/CU, all co-resident (proven in r2-r4).
  gru_persist<<<dim3(NG * WC), dim3(128), SMEM_BYTES, stream>>>(
      x, Wg, bg, Wh, bh, Wo1, bo1, Wo2, bo2, out, ws);
}

// Round 8
// 4271.835 us; speedup vs baseline: 4.2844x; 1.2536x over previous
//
#include <hip/hip_runtime.h>
#include <hip/hip_bf16.h>
#include <stdint.h>

typedef float f32x4 __attribute__((ext_vector_type(4)));
typedef short bf16x8 __attribute__((ext_vector_type(8)));
typedef int   i32x4  __attribute__((ext_vector_type(4)));

#define DEVINL static __device__ __forceinline__

// ---------------- problem dims ----------------
constexpr int BATCH = 256, SEQ = 512, IDIM = 512, HDIM = 512;
constexpr int NG = 8, WC = 32, RPG = 32, CPW = 16;

// ---------------- LDS map (bytes) ----------------
constexpr int WGS_OFF = 0;        // Wg stripe [32 cols][1024 k] bf16 (64KB), XOR-swizzled
constexpr int WHS_OFF = 65536;    // Wh stripe [16 cols][1024 k] bf16 (32KB)
constexpr int WO1_OFF = 98304;    // Wo1 stripe [16 cols][512 k] bf16 (16KB, cols 8..15 zero)
constexpr int XPOSE_OFF = 114688; // 2 waves x 640B repack buffers
constexpr int SMEM_BYTES = XPOSE_OFF + 2 * 640;   // 115968

// ---------------- ws map (bytes) ----------------
// flags: per group 512B: fA at g*512 (u32[mt*32+j]), fB at g*512+256.
// Wave (g,j,mt) polls only its own 128B mt-region (32 slots).
constexpr size_t WS_ZERO = 4096;              // flag arrays (memset each call)
constexpr size_t HBF_OFF  = 8192;             // bf16 h   [256][512] (256KB), no init needed
constexpr size_t RHBF_OFF = HBF_OFF + 262144; // bf16 r*h [256][512] (256KB), no init needed
constexpr size_t WS_NEEDED = RHBF_OFF + 262144;

DEVINL short f2bf(float f) {
  uint32_t u = __float_as_uint(f);
  u += 0x7FFFu + ((u >> 16) & 1u);   // RNE
  return (short)(u >> 16);
}
DEVINL int wgs_off(int c, int k) { return WGS_OFF + c * 2048 + ((k * 2) ^ ((c & 7) << 4)); }
DEVINL int whs_off(int c, int k) { return WHS_OFF + c * 2048 + ((k * 2) ^ ((c & 7) << 4)); }
DEVINL int wo1_off(int c, int k) { return WO1_OFF + c * 1024 + ((k * 2) ^ ((c & 7) << 4)); }
DEVINL float sigm(float v) { return 1.f / (1.f + __expf(-v)); }
DEVINL bf16x8 asbf(i32x4 v) { return __builtin_bit_cast(bf16x8, v); }

// ---------------- flag / exchange primitives (agent scope: sc1) ----------------
// data-complete fence, then publish flag word
DEVINL void flag_pub(uint32_t* p, uint32_t v) {
  asm volatile("s_waitcnt vmcnt(0) lgkmcnt(0)\n\tglobal_store_dword %0, %1, off sc1"
               :: "v"(p), "v"(v) : "memory");
}
// poll this wave's 32-slot region (2 cache lines). Throttled + bounded.
DEVINL void poll32(const uint32_t* base, uint32_t target) {
  const uint32_t* p = base + (threadIdx.x & 31);
  int iter = 0;
  for (;;) {
    uint32_t v;
    asm volatile("global_load_dword %0, %1, off sc1\n\ts_waitcnt vmcnt(0)"
                 : "=v"(v) : "v"(p) : "memory");
    if (__all((int)(v >= target))) break;
    if (++iter > 20000) break;           // bounded: pathology -> fast fail, not timeout
    __builtin_amdgcn_s_sleep(1);         // throttle the IC read-storm
  }
  __builtin_amdgcn_sched_barrier(0);
}
// repack 16x16 bf16 tile through private LDS slice -> 8B/lane coalesced store
DEVINL void publish16x16(char* smem, int xpose, short* dst, int grow, int colbase,
                         int lane, const float* vals) {
  const int q = lane >> 4, lc = lane & 15;
#pragma unroll
  for (int ri = 0; ri < 4; ++ri)
    *(short*)(smem + xpose + (q * 4 + ri) * 40 + lc * 2) = f2bf(vals[ri]);
  asm volatile("s_waitcnt lgkmcnt(0)" ::: "memory");
  __builtin_amdgcn_sched_barrier(0);
  const int rl = lane >> 2, cq = lane & 3;
  unsigned long long d = *(const unsigned long long*)(smem + xpose + rl * 40 + cq * 8);
  short* gp = dst + (size_t)(grow + rl) * HDIM + colbase + cq * 4;
  asm volatile("global_store_dwordx2 %0, %1, off sc1" :: "v"(gp), "v"(d) : "memory");
}
#define GLD16(dst, ptr, imm) \
  asm volatile("global_load_dwordx4 %0, %1, off offset:" imm " sc1" : "=v"(dst) : "v"(ptr))
#define GLD_ALL16(arr, ptr) do { \
  GLD16(arr[0],  ptr, "0");   GLD16(arr[1],  ptr, "64");  \
  GLD16(arr[2],  ptr, "128"); GLD16(arr[3],  ptr, "192"); \
  GLD16(arr[4],  ptr, "256"); GLD16(arr[5],  ptr, "320"); \
  GLD16(arr[6],  ptr, "384"); GLD16(arr[7],  ptr, "448"); \
  GLD16(arr[8],  ptr, "512"); GLD16(arr[9],  ptr, "576"); \
  GLD16(arr[10], ptr, "640"); GLD16(arr[11], ptr, "704"); \
  GLD16(arr[12], ptr, "768"); GLD16(arr[13], ptr, "832"); \
  GLD16(arr[14], ptr, "896"); GLD16(arr[15], ptr, "960"); \
  asm volatile("s_waitcnt vmcnt(0)" ::: "memory"); \
  __builtin_amdgcn_sched_barrier(0); \
} while (0)

#define MFMA(a, b, c) __builtin_amdgcn_mfma_f32_16x16x32_bf16((a), (b), (c), 0, 0, 0)
#define LDB(off) (*(const bf16x8*)(smem + (off)))

__global__ void __launch_bounds__(256, 1) init_ys_kernel(float* out, const float* bo2) {
  int i = blockIdx.x * 256 + threadIdx.x;
  if (i < BATCH * SEQ) out[i] = bo2[0];
}

__global__ void __launch_bounds__(128, 1) gru_persist(
    const float* __restrict__ x,  const float* __restrict__ Wg, const float* __restrict__ bg,
    const float* __restrict__ Wh, const float* __restrict__ bh,
    const float* __restrict__ Wo1,const float* __restrict__ bo1,
    const float* __restrict__ Wo2,const float* __restrict__ bo2,
    float* __restrict__ out, char* __restrict__ ws)
{
  extern __shared__ char smem[];
  const int bid  = blockIdx.x;
  const int gi   = bid & 7;        // group; bid&7 keeps a group's x rows on one XCD's L2 (perf-only)
  const int j    = bid >> 3;       // 0..31 within group
  const int tid  = threadIdx.x;
  const int lane = tid & 63;
  const int mt   = tid >> 6;       // wave 0,1 = M-tile
  const int rowbase = gi * RPG;
  const int colbase = j * CPW;

  short* hbf  = (short*)(ws + HBF_OFF);
  short* rhbf = (short*)(ws + RHBF_OFF);
  uint32_t* fA = (uint32_t*)(ws + (size_t)gi * 512);
  uint32_t* fB = (uint32_t*)(ws + (size_t)gi * 512 + 256);
  const uint32_t* fAmine = fA + mt * 32;   // this wave's poll region (its 16 rows' producers)
  const uint32_t* fBmine = fB + mt * 32;
  uint32_t* myA = fA + (mt * 32 + j);
  uint32_t* myB = fB + (mt * 32 + j);

  // ---------------- init: weights -> LDS (128 threads) ----------------
  for (int it = 0; it < 256; ++it) {
    int cc = tid & 31;
    int k = (tid >> 5) + it * 4;
    int cg = (cc < 16) ? (colbase + cc) : (512 + colbase + (cc - 16));
    *(short*)(smem + wgs_off(cc, k)) = f2bf(Wg[(size_t)k * 1024 + cg]);
  }
  for (int it = 0; it < 128; ++it) {
    int cc = tid & 15;
    int k = (tid >> 4) + it * 8;
    *(short*)(smem + whs_off(cc, k)) = f2bf(Wh[(size_t)k * 512 + colbase + cc]);
  }
  for (int it = 0; it < 64; ++it) {
    int cc = tid & 15;
    int k = (tid >> 4) + it * 8;
    *(short*)(smem + wo1_off(cc, k)) = (cc < 8) ? f2bf(Wo1[(size_t)k * 256 + j * 8 + cc]) : (short)0;
  }

  const int lc = lane & 15;
  const float bgu  = bg[colbase + lc];
  const float bgr  = bg[512 + colbase + lc];
  const float bhc  = bh[colbase + lc];
  const float bo1c = (lc < 8) ? bo1[j * 8 + lc] : 0.f;
  const float wo2c = (lc < 8) ? Wo2[j * 8 + lc] : 0.f;
  __syncthreads();   // the ONLY block barrier

  const int arow  = mt * 16 + lc;          // A-frag row (local)
  const int kl    = (lane >> 4) * 8;       // frag k sub-offset
  const int xpose = XPOSE_OFF + mt * 640;
  const int grow  = rowbase + mt * 16;

  const char* hfrag  = (const char*)(hbf  + (size_t)(rowbase + arow) * HDIM + kl);
  const char* rhfrag = (const char*)(rhbf + (size_t)(rowbase + arow) * HDIM + kl);

  float hreg[4] = {0.f, 0.f, 0.f, 0.f};
  for (int t = 0; t < SEQ; ++t) {
    // ---- x A-frags + gates-x MFMAs (overlap the fB wait window) ----
    bf16x8 xa[16];
    {
      const float* xrow = x + ((size_t)(rowbase + arow) * SEQ + t) * IDIM + kl;
#pragma unroll
      for (int ks = 0; ks < 16; ++ks) {
        float4 a = *(const float4*)(xrow + ks * 32);
        float4 b = *(const float4*)(xrow + ks * 32 + 4);
        bf16x8 v;
        v[0] = f2bf(a.x); v[1] = f2bf(a.y); v[2] = f2bf(a.z); v[3] = f2bf(a.w);
        v[4] = f2bf(b.x); v[5] = f2bf(b.y); v[6] = f2bf(b.z); v[7] = f2bf(b.w);
        xa[ks] = v;
      }
    }
    f32x4 gu0 = {0,0,0,0}, gu1 = {0,0,0,0}, gr0 = {0,0,0,0}, gr1 = {0,0,0,0};
#pragma unroll
    for (int ks = 0; ks < 16; ks += 2) {
      gu0 = MFMA(xa[ks],   LDB(wgs_off(lc, ks * 32 + kl)),            gu0);
      gu1 = MFMA(xa[ks+1], LDB(wgs_off(lc, (ks + 1) * 32 + kl)),      gu1);
      gr0 = MFMA(xa[ks],   LDB(wgs_off(16 + lc, ks * 32 + kl)),       gr0);
      gr1 = MFMA(xa[ks+1], LDB(wgs_off(16 + lc, (ks + 1) * 32 + kl)), gr1);
    }
    // ---- hop B: h_{t-1} ----
    i32x4 ha[16];
    if (t) {
      poll32(fBmine, (uint32_t)t);
      GLD_ALL16(ha, hfrag);
#pragma unroll
      for (int ks = 0; ks < 16; ks += 2) {
        gu0 = MFMA(asbf(ha[ks]),   LDB(wgs_off(lc, 512 + ks * 32 + kl)),            gu0);
        gu1 = MFMA(asbf(ha[ks+1]), LDB(wgs_off(lc, 512 + (ks + 1) * 32 + kl)),      gu1);
        gr0 = MFMA(asbf(ha[ks]),   LDB(wgs_off(16 + lc, 512 + ks * 32 + kl)),       gr0);
        gr1 = MFMA(asbf(ha[ks+1]), LDB(wgs_off(16 + lc, 512 + (ks + 1) * 32 + kl)), gr1);
      }
    }
    f32x4 gu = gu0 + gu1, gr = gr0 + gr1;
    float uv[4], rhv[4];
#pragma unroll
    for (int ri = 0; ri < 4; ++ri) {
      uv[ri]  = sigm(gu[ri] + bgu);
      rhv[ri] = sigm(gr[ri] + bgr) * hreg[ri];
    }
    if (t) {   // rh(0)=0 group-wide: no publish/consume at t=0
      publish16x16(smem, xpose, rhbf, grow, colbase, lane, rhv);
      flag_pub(myA, (uint32_t)(t + 1));
    }
    // ---- fA shadow: head MFMAs + cand-x MFMAs ----
    f32x4 hd0 = {0,0,0,0}, hd1 = {0,0,0,0};
    if (t) {
#pragma unroll
      for (int ks = 0; ks < 16; ks += 2) {
        hd0 = MFMA(asbf(ha[ks]),   LDB(wo1_off(lc, ks * 32 + kl)),       hd0);
        hd1 = MFMA(asbf(ha[ks+1]), LDB(wo1_off(lc, (ks + 1) * 32 + kl)), hd1);
      }
    }
    f32x4 cx0 = {0,0,0,0}, cx1 = {0,0,0,0};
#pragma unroll
    for (int ks = 0; ks < 16; ks += 2) {
      cx0 = MFMA(xa[ks],   LDB(whs_off(lc, ks * 32 + kl)),       cx0);
      cx1 = MFMA(xa[ks+1], LDB(whs_off(lc, (ks + 1) * 32 + kl)), cx1);
    }
    // ---- hop A: r*h ----
    f32x4 ch0 = {0,0,0,0}, ch1 = {0,0,0,0};
    if (t) {
      poll32(fAmine, (uint32_t)(t + 1));
      i32x4 ra[16];
      GLD_ALL16(ra, rhfrag);
#pragma unroll
      for (int ks = 0; ks < 16; ks += 2) {
        ch0 = MFMA(asbf(ra[ks]),   LDB(whs_off(lc, 512 + ks * 32 + kl)),       ch0);
        ch1 = MFMA(asbf(ra[ks+1]), LDB(whs_off(lc, 512 + (ks + 1) * 32 + kl)), ch1);
      }
    }
    f32x4 cc = cx0 + cx1 + ch0 + ch1;
    float hnv[4];
#pragma unroll
    for (int ri = 0; ri < 4; ++ri) {
      float cand = tanhf(cc[ri] + bhc);
      float hnew = hreg[ri] + uv[ri] * (cand - hreg[ri]);
      hreg[ri] = hnew; hnv[ri] = hnew;
      if (t == SEQ - 1) {
        int row = mt * 16 + (lane >> 4) * 4 + ri;
        out[(size_t)(BATCH * SEQ) + (size_t)(rowbase + row) * HDIM + colbase + lc] = hnew;
      }
    }
    publish16x16(smem, xpose, hbf, grow, colbase, lane, hnv);
    flag_pub(myB, (uint32_t)(t + 1));
    // ---- finish head y_{t-1}; atomics after fB pub (off the drain path) ----
    if (t) {
      f32x4 d = hd0 + hd1;
#pragma unroll
      for (int ri = 0; ri < 4; ++ri) {
        float z = fmaxf(d[ri] + bo1c, 0.f) * wo2c;
        z += __shfl_xor(z, 1); z += __shfl_xor(z, 2);
        z += __shfl_xor(z, 4); z += __shfl_xor(z, 8);
        if (lc == 0) {
          int row = rowbase + mt * 16 + (lane >> 4) * 4 + ri;
          unsafeAtomicAdd(&out[(size_t)row * SEQ + (t - 1)], z);
        }
      }
    }
  }
  // ---- epilogue: y_{SEQ-1} ----
  poll32(fBmine, (uint32_t)SEQ);
  i32x4 ha[16];
  GLD_ALL16(ha, hfrag);
  f32x4 hd0 = {0,0,0,0}, hd1 = {0,0,0,0};
#pragma unroll
  for (int ks = 0; ks < 16; ks += 2) {
    hd0 = MFMA(asbf(ha[ks]),   LDB(wo1_off(lc, ks * 32 + kl)),       hd0);
    hd1 = MFMA(asbf(ha[ks+1]), LDB(wo1_off(lc, (ks + 1) * 32 + kl)), hd1);
  }
  f32x4 d = hd0 + hd1;
#pragma unroll
  for (int ri = 0; ri < 4; ++ri) {
    float z = fmaxf(d[ri] + bo1c, 0.f) * wo2c;
    z += __shfl_xor(z, 1); z += __shfl_xor(z, 2);
    z += __shfl_xor(z, 4); z += __shfl_xor(z, 8);
    if (lc == 0) {
      int row = rowbase + mt * 16 + (lane >> 4) * 4 + ri;
      unsafeAtomicAdd(&out[(size_t)row * SEQ + (SEQ - 1)], z);
    }
  }
}

extern "C" void kernel_launch(void* const* d_in, const int* in_sizes, int n_in,
                              void* d_out, int out_size, void* d_ws, size_t ws_size,
                              hipStream_t stream) {
  const float* x   = (const float*)d_in[0];
  const float* Wg  = (const float*)d_in[1];
  const float* bg  = (const float*)d_in[2];
  const float* Wh  = (const float*)d_in[3];
  const float* bh  = (const float*)d_in[4];
  const float* Wo1 = (const float*)d_in[5];
  const float* bo1 = (const float*)d_in[6];
  const float* Wo2 = (const float*)d_in[7];
  const float* bo2 = (const float*)d_in[8];
  float* out = (float*)d_out;
  char*  ws  = (char*)d_ws;
  if (ws_size < WS_NEEDED) return;

  hipMemsetAsync(ws, 0, WS_ZERO, stream);      // flag arrays
  init_ys_kernel<<<dim3(512), dim3(256), 0, stream>>>(out, bo2);

  (void)hipFuncSetAttribute((const void*)gru_persist,
                            hipFuncAttributeMaxDynamicSharedMemorySize, SMEM_BYTES);

  // 256 blocks x ~113KB LDS -> 1 block/CU, all co-resident (proven r2-r7).
  gru_persist<<<dim3(NG * WC), dim3(128), SMEM_BYTES, stream>>>(
      x, Wg, bg, Wh, bh, Wo1, bo1, Wo2, bo2, out, ws);
}